// Round 18
// baseline (182.867 us; speedup 1.0000x reference)
//
#include <hip/hip_runtime.h>
#include <hip/hip_bf16.h>

#define N_NODES 100000
#define N_EDGES 1600000
#define D 64  // D_IN == D_OUT == 64

// ---- bucket machinery (Tier A) ----
#define NB 160                          // stream blocks for hist/scatter (R13 optimum)
#define CH (N_EDGES / NB)               // 10000 edges per block
#define CH4 (CH / 4)                    // 2500 int4 groups per block
#define BSH 6                           // 64 nodes per bucket
#define BNODES 64
#define NBUCK 1563                      // ceil(100000/64)
#define NBUCKP 1568                     // padded
#define BCAP 2560                       // LDS bin cap (bucket edges ~Poisson(1024))

// ---- Tier B fallback constants (R7 path) ----
#define NPART 8
#define PART_N (N_NODES / NPART)
#define TOTAL_I4 (N_EDGES / 4)
#define GK_BLOCKS 4096
#define SCAN_BS 256
#define SCAN_ITEMS 4
#define SCAN_TILE (SCAN_BS * SCAN_ITEMS)
#define SCAN_NBLK ((N_NODES + SCAN_TILE - 1) / SCAN_TILE)

typedef unsigned short ushort8v __attribute__((ext_vector_type(8)));

__device__ __forceinline__ unsigned short f2bf_rne(float f) {
    unsigned u = __float_as_uint(f);
    u += 0x7fffu + ((u >> 16) & 1u);
    return (unsigned short)(u >> 16);
}

// ---------------------------------------------------------------------------
// Phase 1: per-block LDS histograms of src/dst buckets (int4 edge loads).
// Block 0 zeroes the two global base cursors used by colscan2.
// ---------------------------------------------------------------------------
__global__ void __launch_bounds__(512) hist_kernel(const int* __restrict__ src,
                                                   const int* __restrict__ dst,
                                                   unsigned int* __restrict__ Hs,
                                                   unsigned int* __restrict__ Hd,
                                                   unsigned int* __restrict__ cursors) {
    __shared__ unsigned hs[NBUCKP], hd[NBUCKP];
    int t = threadIdx.x;
    if (blockIdx.x == 0 && t < 8) cursors[t] = 0u;
    for (int i = t; i < NBUCKP; i += 512) { hs[i] = 0u; hd[i] = 0u; }
    __syncthreads();
    int base = blockIdx.x * CH4;
    for (int i = base + t; i < base + CH4; i += 512) {
        const int4 s4 = reinterpret_cast<const int4*>(src)[i];
        const int4 d4 = reinterpret_cast<const int4*>(dst)[i];
        atomicAdd(&hs[(unsigned)s4.x >> BSH], 1u);
        atomicAdd(&hs[(unsigned)s4.y >> BSH], 1u);
        atomicAdd(&hs[(unsigned)s4.z >> BSH], 1u);
        atomicAdd(&hs[(unsigned)s4.w >> BSH], 1u);
        atomicAdd(&hd[(unsigned)d4.x >> BSH], 1u);
        atomicAdd(&hd[(unsigned)d4.y >> BSH], 1u);
        atomicAdd(&hd[(unsigned)d4.z >> BSH], 1u);
        atomicAdd(&hd[(unsigned)d4.w >> BSH], 1u);
    }
    __syncthreads();
    unsigned int* rs = Hs + (size_t)blockIdx.x * NBUCKP;
    unsigned int* rd = Hd + (size_t)blockIdx.x * NBUCKP;
    for (int i = t; i < NBUCKP; i += 512) { rs[i] = hs[i]; rd[i] = hd[i]; }
}

// ---------------------------------------------------------------------------
// Phase 2 (fused s+d, atomic bases): per-bucket exclusive scan over the NB
// blocks (in place) + totals + bucket base via global atomic cursor.
// Bases are dispatch-order-dependent BUT output stays bitwise-deterministic:
// each bucket's segment content and within-segment order are unchanged.
// Grid = 2*NBUCKP. Replaces colscan2 + totscan (one fewer launch).
// ---------------------------------------------------------------------------
__global__ void __launch_bounds__(256) colscan2_kernel(unsigned int* __restrict__ Hs,
                                                       unsigned int* __restrict__ Hd,
                                                       unsigned int* __restrict__ total_s,
                                                       unsigned int* __restrict__ total_d,
                                                       unsigned int* __restrict__ cbase_s,
                                                       unsigned int* __restrict__ cbase_d,
                                                       unsigned int* __restrict__ cursors) {
    __shared__ unsigned sh[256];
    int arr = (blockIdx.x >= NBUCKP) ? 1 : 0;
    int b = blockIdx.x - arr * NBUCKP;
    unsigned int* H     = arr ? Hd : Hs;
    unsigned int* total = arr ? total_d : total_s;
    unsigned int* cbase = arr ? cbase_d : cbase_s;
    int t = threadIdx.x;
    unsigned v = (t < NB) ? H[(size_t)t * NBUCKP + b] : 0u;
    sh[t] = v;
    __syncthreads();
    for (int off = 1; off < 256; off <<= 1) {
        unsigned x = (t >= off) ? sh[t - off] : 0u;
        __syncthreads();
        sh[t] += x;
        __syncthreads();
    }
    if (t < NB) H[(size_t)t * NBUCKP + b] = sh[t] - v;   // exclusive
    if (t == NB - 1) {
        total[b] = sh[t];
        cbase[b] = atomicAdd(&cursors[arr], sh[t]);      // unordered base
    }
}

// ---------------------------------------------------------------------------
// Phase 3: scatter edges into bucket-sorted arrays (int4 edge loads, LDS
// cursors, run-coalesced global writes, zero global atomics).
// sbuck (uint8): srcLocal; dbuck: dstLocal<<17|src
// ---------------------------------------------------------------------------
__global__ void __launch_bounds__(512) scatter_kernel(const int* __restrict__ src,
                                                      const int* __restrict__ dst,
                                                      const unsigned int* __restrict__ Hs,
                                                      const unsigned int* __restrict__ Hd,
                                                      const unsigned int* __restrict__ cbase_s,
                                                      const unsigned int* __restrict__ cbase_d,
                                                      unsigned char* __restrict__ sbuck,
                                                      unsigned int* __restrict__ dbuck) {
    __shared__ unsigned cs[NBUCKP], cd[NBUCKP];
    int t = threadIdx.x;
    int blk = blockIdx.x;
    const unsigned int* rs = Hs + (size_t)blk * NBUCKP;
    const unsigned int* rd = Hd + (size_t)blk * NBUCKP;
    for (int i = t; i < NBUCKP; i += 512) {
        cs[i] = cbase_s[i] + rs[i];
        cd[i] = cbase_d[i] + rd[i];
    }
    __syncthreads();
    int base = blk * CH4;
    for (int i = base + t; i < base + CH4; i += 512) {
        const int4 s4 = reinterpret_cast<const int4*>(src)[i];
        const int4 d4 = reinterpret_cast<const int4*>(dst)[i];
        #define SCAT1(S, Dd)                                              \
            {                                                             \
                unsigned ps = atomicAdd(&cs[(unsigned)(S) >> BSH], 1u);   \
                sbuck[ps] = (unsigned char)((unsigned)(S) & (BNODES - 1)); \
                unsigned pd = atomicAdd(&cd[(unsigned)(Dd) >> BSH], 1u);  \
                dbuck[pd] = (((unsigned)(Dd) & (BNODES - 1)) << 17) | (unsigned)(S); \
            }
        SCAT1(s4.x, d4.x)
        SCAT1(s4.y, d4.y)
        SCAT1(s4.z, d4.z)
        SCAT1(s4.w, d4.w)
        #undef SCAT1
    }
}

// ---------------------------------------------------------------------------
// Phase 4a (fused degcnt + g): per src-bucket, LDS-count out-degrees from
// sbuck, then g[r] = bf16( (feat[r]*rsqrt(max(deg,1))) @ W^T ) for the
// bucket's 64 nodes. W-row load hoisted before the sync to overlap.
// ---------------------------------------------------------------------------
__global__ void __launch_bounds__(256) gprep_kernel(const unsigned char* __restrict__ sbuck,
                                                    const unsigned int* __restrict__ cbase_s,
                                                    const unsigned int* __restrict__ total_s,
                                                    const float* __restrict__ feat,
                                                    const float* __restrict__ W,
                                                    unsigned short* __restrict__ g) {
    __shared__ unsigned cnt[BNODES];
    int bk = blockIdx.x;
    int t = threadIdx.x;
    int w = t >> 6;
    int lane = t & 63;
    if (t < BNODES) cnt[t] = 0u;
    __syncthreads();
    unsigned base = cbase_s[bk];
    unsigned n = total_s[bk];
    for (unsigned i = t; i < n; i += 256) {
        atomicAdd(&cnt[sbuck[base + i]], 1u);   // LDS atomic
    }

    float wreg[D];
    #pragma unroll
    for (int q = 0; q < 16; ++q) {
        const float4 t4 = *reinterpret_cast<const float4*>(&W[(size_t)lane * D + q * 4]);
        wreg[q * 4 + 0] = t4.x;
        wreg[q * 4 + 1] = t4.y;
        wreg[q * 4 + 2] = t4.z;
        wreg[q * 4 + 3] = t4.w;
    }
    __syncthreads();

    for (int nl = w; nl < BNODES; nl += 4) {
        int node = bk * BNODES + nl;
        if (node >= N_NODES) break;          // wave-uniform
        unsigned dg = cnt[nl];
        float sc = rsqrtf((float)(dg > 0u ? dg : 1u));
        float fv = feat[(size_t)node * D + lane] * sc;
        float o = 0.f;
        #pragma unroll
        for (int k = 0; k < D; ++k) {
            float fk = __int_as_float(
                __builtin_amdgcn_readlane(__float_as_int(fv), k));
            o += fk * wreg[k];
        }
        g[(size_t)node * D + lane] = f2bf_rne(o);
    }
}

// ---------------------------------------------------------------------------
// Phase 4b: per dst-bucket fused LDS-CSR + gather-sum + bias + rsqrt(deg_in).
// R13-proven: 256 threads, ONE block per bucket, dual-node interleave.
// ---------------------------------------------------------------------------
__global__ void __launch_bounds__(256) gsum_bucket(const unsigned short* __restrict__ g,
                                                   const unsigned int* __restrict__ dbuck,
                                                   const unsigned int* __restrict__ cbase_d,
                                                   const unsigned int* __restrict__ total_d,
                                                   const float* __restrict__ b,
                                                   float* __restrict__ out) {
    __shared__ int binned[BCAP];
    __shared__ unsigned cnt[BNODES], offs[BNODES], cur[BNODES];
    int bk = blockIdx.x;
    int t = threadIdx.x;
    int w = t >> 6;
    int lane = t & 63;
    int slot = lane >> 3;
    int sub  = lane & 7;

    if (t < BNODES) cnt[t] = 0u;
    __syncthreads();

    unsigned base = cbase_d[bk];
    unsigned n = total_d[bk];
    if (n > (unsigned)BCAP) n = BCAP;   // astronomically improbable clamp

    // count pass
    for (unsigned i = t; i < n; i += 256) {
        atomicAdd(&cnt[dbuck[base + i] >> 17], 1u);   // LDS atomic
    }
    __syncthreads();
    // inclusive scan of cnt[64] -> offs
    if (t < BNODES) offs[t] = cnt[t];
    __syncthreads();
    for (int off = 1; off < BNODES; off <<= 1) {
        unsigned x = (t < BNODES && t >= off) ? offs[t - off] : 0u;
        __syncthreads();
        if (t < BNODES) offs[t] += x;
        __syncthreads();
    }
    if (t < BNODES) cur[t] = offs[t] - cnt[t];        // exclusive base
    __syncthreads();
    // place pass
    for (unsigned i = t; i < n; i += 256) {
        unsigned p = dbuck[base + i];
        unsigned d = p >> 17;
        unsigned pos = atomicAdd(&cur[d], 1u);        // LDS atomic
        binned[pos] = (int)(p & 0x1FFFFu);
    }
    __syncthreads();

    float breg = b[sub * 8 + slot];
    // two nodes per wave-iteration: nlA in [0,32), nlB = nlA+32
    for (int j = 0; j < 8; ++j) {
        int nlA = w + 4 * j;
        int nlB = nlA + 32;
        int nodeA = bk * BNODES + nlA;
        int nodeB = bk * BNODES + nlB;
        bool okA = (nodeA < N_NODES);
        bool okB = (nodeB < N_NODES);
        unsigned degA = okA ? cnt[nlA] : 0u;
        unsigned degB = okB ? cnt[nlB] : 0u;
        unsigned eoffA = okA ? (offs[nlA] - degA) : 0u;
        unsigned eoffB = okB ? (offs[nlB] - degB) : 0u;
        unsigned dmax = degA > degB ? degA : degB;

        float accA[8], accB[8];
        #pragma unroll
        for (int q = 0; q < 8; ++q) { accA[q] = 0.f; accB[q] = 0.f; }

        for (unsigned e = 0; e < dmax; e += 8u) {
            unsigned es = e + (unsigned)slot;
            if (es < degA) {
                int s = binned[eoffA + es];            // 8-lane LDS broadcast
                const ushort8v v = *reinterpret_cast<const ushort8v*>(
                    &g[(size_t)s * D + sub * 8]);
                #pragma unroll
                for (int q = 0; q < 8; ++q)
                    accA[q] += __uint_as_float((unsigned)v[q] << 16);
            }
            if (es < degB) {
                int s = binned[eoffB + es];
                const ushort8v v = *reinterpret_cast<const ushort8v*>(
                    &g[(size_t)s * D + sub * 8]);
                #pragma unroll
                for (int q = 0; q < 8; ++q)
                    accB[q] += __uint_as_float((unsigned)v[q] << 16);
            }
        }

        #pragma unroll
        for (int q = 0; q < 8; ++q) {
            accA[q] += __shfl_xor(accA[q], 8);
            accA[q] += __shfl_xor(accA[q], 16);
            accA[q] += __shfl_xor(accA[q], 32);
            accB[q] += __shfl_xor(accB[q], 8);
            accB[q] += __shfl_xor(accB[q], 16);
            accB[q] += __shfl_xor(accB[q], 32);
        }
        float redA = (slot == 0) ? accA[0] : (slot == 1) ? accA[1] :
                     (slot == 2) ? accA[2] : (slot == 3) ? accA[3] :
                     (slot == 4) ? accA[4] : (slot == 5) ? accA[5] :
                     (slot == 6) ? accA[6] : accA[7];
        float redB = (slot == 0) ? accB[0] : (slot == 1) ? accB[1] :
                     (slot == 2) ? accB[2] : (slot == 3) ? accB[3] :
                     (slot == 4) ? accB[4] : (slot == 5) ? accB[5] :
                     (slot == 6) ? accB[6] : accB[7];
        int X = sub * 8 + slot;
        if (okA) {
            float rs = rsqrtf((float)(degA > 0u ? degA : 1u));
            __builtin_nontemporal_store((redA + breg) * rs,
                                        out + (size_t)nodeA * D + X);
        }
        if (okB) {
            float rs = rsqrtf((float)(degB > 0u ? degB : 1u));
            __builtin_nontemporal_store((redB + breg) * rs,
                                        out + (size_t)nodeB * D + X);
        }
    }
}

// ===========================================================================
// Tier B fallback (R7 path): partitioned atomics + CSR + h table + gather/GEMM
// ===========================================================================
__global__ void __launch_bounds__(256) deg2_part(const int* __restrict__ src,
                                                 const int* __restrict__ dst,
                                                 unsigned int* __restrict__ deg_out,
                                                 unsigned int* __restrict__ deg_in) {
    int part  = blockIdx.x & (NPART - 1);
    int chunk = blockIdx.x >> 3;
    unsigned lo = (unsigned)(part * PART_N);
    int base = chunk * (TOTAL_I4 / 250);
    for (int i = base + (int)threadIdx.x; i < base + (TOTAL_I4 / 250); i += 256) {
        const int4 s4 = reinterpret_cast<const int4*>(src)[i];
        const int4 d4 = reinterpret_cast<const int4*>(dst)[i];
        if ((unsigned)(s4.x - lo) < (unsigned)PART_N) atomicAdd(&deg_out[s4.x], 1u);
        if ((unsigned)(s4.y - lo) < (unsigned)PART_N) atomicAdd(&deg_out[s4.y], 1u);
        if ((unsigned)(s4.z - lo) < (unsigned)PART_N) atomicAdd(&deg_out[s4.z], 1u);
        if ((unsigned)(s4.w - lo) < (unsigned)PART_N) atomicAdd(&deg_out[s4.w], 1u);
        if ((unsigned)(d4.x - lo) < (unsigned)PART_N) atomicAdd(&deg_in[d4.x], 1u);
        if ((unsigned)(d4.y - lo) < (unsigned)PART_N) atomicAdd(&deg_in[d4.y], 1u);
        if ((unsigned)(d4.z - lo) < (unsigned)PART_N) atomicAdd(&deg_in[d4.z], 1u);
        if ((unsigned)(d4.w - lo) < (unsigned)PART_N) atomicAdd(&deg_in[d4.w], 1u);
    }
}

__global__ void __launch_bounds__(SCAN_BS) scan1_kernel(
        const unsigned int* __restrict__ in,
        unsigned int* __restrict__ out,
        unsigned int* __restrict__ partials, int n) {
    __shared__ unsigned int ssum[SCAN_BS];
    int t = threadIdx.x;
    int base = blockIdx.x * SCAN_TILE + t * SCAN_ITEMS;
    unsigned int v[SCAN_ITEMS];
    unsigned int s = 0;
    #pragma unroll
    for (int k = 0; k < SCAN_ITEMS; ++k) {
        v[k] = (base + k < n) ? in[base + k] : 0u;
        s += v[k];
    }
    ssum[t] = s;
    __syncthreads();
    for (int off = 1; off < SCAN_BS; off <<= 1) {
        unsigned int x = (t >= off) ? ssum[t - off] : 0u;
        __syncthreads();
        ssum[t] += x;
        __syncthreads();
    }
    unsigned int excl = (t == 0) ? 0u : ssum[t - 1];
    if (t == SCAN_BS - 1) partials[blockIdx.x] = ssum[t];
    unsigned int run = excl;
    #pragma unroll
    for (int k = 0; k < SCAN_ITEMS; ++k) {
        if (base + k < n) out[base + k] = run;
        run += v[k];
    }
}

__global__ void __launch_bounds__(128) scan2_kernel(
        unsigned int* __restrict__ partials, int nb) {
    __shared__ unsigned int sh[128];
    int t = threadIdx.x;
    unsigned int v = (t < nb) ? partials[t] : 0u;
    sh[t] = v;
    __syncthreads();
    for (int off = 1; off < 128; off <<= 1) {
        unsigned int x = (t >= off) ? sh[t - off] : 0u;
        __syncthreads();
        sh[t] += x;
        __syncthreads();
    }
    if (t < nb) partials[t] = (t == 0) ? 0u : sh[t - 1];
}

__global__ void scan3_kernel(unsigned int* __restrict__ offsets,
                             const unsigned int* __restrict__ partials,
                             unsigned int* __restrict__ cursor, int n) {
    int i = blockIdx.x * blockDim.x + threadIdx.x;
    if (i < n) {
        unsigned int v = offsets[i] + partials[i / SCAN_TILE];
        offsets[i] = v;
        cursor[i]  = v;
    }
    if (i == 0) offsets[n] = N_EDGES;
}

__global__ void __launch_bounds__(256) place_part(const int* __restrict__ src,
                                                  const int* __restrict__ dst,
                                                  unsigned int* __restrict__ cursor,
                                                  int* __restrict__ sorted_src) {
    int part  = blockIdx.x & (NPART - 1);
    int chunk = blockIdx.x >> 3;
    unsigned lo = (unsigned)(part * PART_N);
    int base = chunk * (TOTAL_I4 / 250);
    for (int i = base + (int)threadIdx.x; i < base + (TOTAL_I4 / 250); i += 256) {
        const int4 s4 = reinterpret_cast<const int4*>(src)[i];
        const int4 d4 = reinterpret_cast<const int4*>(dst)[i];
        #define PLACE1(S, Dd)                                             \
            if ((unsigned)((unsigned)(Dd) - lo) < (unsigned)PART_N) {     \
                unsigned p = atomicAdd(&cursor[(Dd)], 1u);                \
                sorted_src[p] = (S);                                      \
            }
        PLACE1(s4.x, d4.x)
        PLACE1(s4.y, d4.y)
        PLACE1(s4.z, d4.z)
        PLACE1(s4.w, d4.w)
        #undef PLACE1
    }
}

__global__ void h_kernel(const float* __restrict__ feat,
                         const unsigned int* __restrict__ deg_out,
                         unsigned short* __restrict__ h) {
    int tid = blockIdx.x * blockDim.x + threadIdx.x;
    if (tid >= N_NODES * 16) return;
    int node = tid >> 4;
    unsigned int dg = deg_out[node];
    float sc = rsqrtf((float)(dg > 0u ? dg : 1u));
    const float4 v = *reinterpret_cast<const float4*>(&feat[(size_t)tid * 4]);
    ushort4 o;
    o.x = f2bf_rne(v.x * sc);
    o.y = f2bf_rne(v.y * sc);
    o.z = f2bf_rne(v.z * sc);
    o.w = f2bf_rne(v.w * sc);
    *reinterpret_cast<ushort4*>(&h[(size_t)tid * 4]) = o;
}

__global__ void __launch_bounds__(256) gg2_kernel(
        const unsigned short* __restrict__ h,
        const int* __restrict__ sorted_src,
        const unsigned int* __restrict__ offsets,
        const float* __restrict__ W,
        const float* __restrict__ b,
        float* __restrict__ out) {
    int t = threadIdx.x;
    int w = t >> 6;
    int lane = t & 63;
    int slot = lane >> 3;
    int sub  = lane & 7;

    float wreg[D];
    #pragma unroll
    for (int q = 0; q < 16; ++q) {
        const float4 t4 = *reinterpret_cast<const float4*>(&W[(size_t)lane * D + q * 4]);
        wreg[q * 4 + 0] = t4.x;
        wreg[q * 4 + 1] = t4.y;
        wreg[q * 4 + 2] = t4.z;
        wreg[q * 4 + 3] = t4.w;
    }
    float breg = b[lane];

    for (int r = blockIdx.x * 4 + w; r < N_NODES; r += GK_BLOCKS * 4) {
        unsigned int beg = offsets[r];
        unsigned int end = offsets[r + 1];
        unsigned int deg = end - beg;

        float acc[8];
        #pragma unroll
        for (int j = 0; j < 8; ++j) acc[j] = 0.f;

        for (unsigned int base = beg; base < end; base += 64u) {
            int count = (int)(end - base);
            if (count > 64) count = 64;
            int myidx = (lane < count) ? sorted_src[base + lane] : 0;
            for (int e = 0; e < count; e += 8) {
                int es = e + slot;
                int s = __shfl(myidx, es);
                if (es < count) {
                    const ushort8v v = *reinterpret_cast<const ushort8v*>(
                        &h[(size_t)s * D + sub * 8]);
                    #pragma unroll
                    for (int j = 0; j < 8; ++j) {
                        acc[j] += __uint_as_float((unsigned)v[j] << 16);
                    }
                }
            }
        }

        #pragma unroll
        for (int j = 0; j < 8; ++j) {
            acc[j] += __shfl_xor(acc[j], 8);
            acc[j] += __shfl_xor(acc[j], 16);
            acc[j] += __shfl_xor(acc[j], 32);
        }

        float o = breg;
        #pragma unroll
        for (int k = 0; k < D; ++k) {
            float av = __int_as_float(
                __builtin_amdgcn_readlane(__float_as_int(acc[k & 7]), k >> 3));
            o += av * wreg[k];
        }

        out[(size_t)r * D + lane] = o * rsqrtf((float)(deg > 0u ? deg : 1u));
    }
}

// ---------------------------------------------------------------------------
extern "C" void kernel_launch(void* const* d_in, const int* in_sizes, int n_in,
                              void* d_out, int out_size, void* d_ws, size_t ws_size,
                              hipStream_t stream) {
    const float* feat = (const float*)d_in[0];
    const int*   src  = (const int*)d_in[1];
    const int*   dst  = (const int*)d_in[2];
    const float* W    = (const float*)d_in[3];
    const float* b    = (const float*)d_in[4];
    float* out = (float*)d_out;

    // --- Tier A layout (u32 units unless noted) ---
    {
        unsigned int* Hs      = (unsigned int*)d_ws;                    // NB*NBUCKP
        unsigned int* Hd      = Hs + (size_t)NB * NBUCKP;
        unsigned int* total_s = Hd + (size_t)NB * NBUCKP;               // NBUCKP
        unsigned int* cbase_s = total_s + NBUCKP;
        unsigned int* total_d = cbase_s + NBUCKP;
        unsigned int* cbase_d = total_d + NBUCKP;
        unsigned int* cursors = cbase_d + NBUCKP;                       // 8
        unsigned char* sbuck  = (unsigned char*)(cursors + 8);          // N_EDGES bytes
        unsigned int* dbuck   = (unsigned int*)(sbuck + N_EDGES);       // N_EDGES u32
        unsigned short* g     = (unsigned short*)(dbuck + N_EDGES);     // N*64 bf16
        size_t need_A = ((size_t)2 * NB * NBUCKP + 4 * NBUCKP + 8) * 4
                        + (size_t)N_EDGES                                 // sbuck bytes
                        + (size_t)N_EDGES * 4                             // dbuck
                        + (size_t)N_NODES * D * 2;                        // g
        if (ws_size >= need_A) {
            hist_kernel<<<NB, 512, 0, stream>>>(src, dst, Hs, Hd, cursors);
            colscan2_kernel<<<2 * NBUCKP, 256, 0, stream>>>(Hs, Hd, total_s, total_d,
                                                            cbase_s, cbase_d, cursors);
            scatter_kernel<<<NB, 512, 0, stream>>>(src, dst, Hs, Hd,
                                                   cbase_s, cbase_d, sbuck, dbuck);
            gprep_kernel<<<NBUCK, 256, 0, stream>>>(sbuck, cbase_s, total_s, feat, W, g);
            gsum_bucket<<<NBUCK, 256, 0, stream>>>(g, dbuck, cbase_d, total_d, b, out);
            return;
        }
    }

    // --- Tier B layout (R7 fallback path), ~21 MB ---
    unsigned int* deg_out  = (unsigned int*)d_ws;
    unsigned int* deg_in   = deg_out + N_NODES;
    unsigned int* offsets  = deg_in + N_NODES;
    unsigned int* cursor   = offsets + N_NODES + 1;
    unsigned int* partials = cursor + N_NODES;
    size_t hdr = (size_t)(4 * N_NODES + 1 + 128);
    hdr = (hdr + 3u) & ~(size_t)3;
    int* sorted_src = (int*)d_ws + hdr;
    size_t hoff = hdr + N_EDGES;
    unsigned short* h = (unsigned short*)((unsigned int*)d_ws + hoff);

    hipMemsetAsync(d_ws, 0, (size_t)2 * N_NODES * sizeof(unsigned int), stream);
    deg2_part<<<2000, 256, 0, stream>>>(src, dst, deg_out, deg_in);
    scan1_kernel<<<SCAN_NBLK, SCAN_BS, 0, stream>>>(deg_in, offsets, partials, N_NODES);
    scan2_kernel<<<1, 128, 0, stream>>>(partials, SCAN_NBLK);
    scan3_kernel<<<(N_NODES + 255) / 256, 256, 0, stream>>>(offsets, partials, cursor, N_NODES);
    h_kernel<<<(N_NODES * 16 + 255) / 256, 256, 0, stream>>>(feat, deg_out, h);
    place_part<<<2000, 256, 0, stream>>>(src, dst, cursor, sorted_src);
    gg2_kernel<<<GK_BLOCKS, 256, 0, stream>>>(h, sorted_src, offsets, W, b, out);
}

// Round 19
// 151.120 us; speedup vs baseline: 1.2101x; 1.2101x over previous
//
#include <hip/hip_runtime.h>
#include <hip/hip_bf16.h>

#define N_NODES 100000
#define N_EDGES 1600000
#define D 64  // D_IN == D_OUT == 64

// ---- bucket machinery (Tier A) ----
#define NB 160                          // stream blocks for hist/scatter (R13 optimum)
#define CH (N_EDGES / NB)               // 10000 edges per block
#define CH4 (CH / 4)                    // 2500 int4 groups per block
#define BSH 6                           // 64 nodes per bucket
#define BNODES 64
#define NBUCK 1563                      // ceil(100000/64)
#define NBUCKP 1568                     // padded
#define BCAP 2560                       // LDS bin cap (bucket edges ~Poisson(1024))

// ---- Tier B fallback constants (R7 path) ----
#define NPART 8
#define PART_N (N_NODES / NPART)
#define TOTAL_I4 (N_EDGES / 4)
#define GK_BLOCKS 4096
#define SCAN_BS 256
#define SCAN_ITEMS 4
#define SCAN_TILE (SCAN_BS * SCAN_ITEMS)
#define SCAN_NBLK ((N_NODES + SCAN_TILE - 1) / SCAN_TILE)

typedef unsigned short ushort8v __attribute__((ext_vector_type(8)));

__device__ __forceinline__ unsigned short f2bf_rne(float f) {
    unsigned u = __float_as_uint(f);
    u += 0x7fffu + ((u >> 16) & 1u);
    return (unsigned short)(u >> 16);
}

// ---------------------------------------------------------------------------
// Phase 1: per-block LDS histograms of src/dst buckets (int4 edge loads)
// ---------------------------------------------------------------------------
__global__ void __launch_bounds__(512) hist_kernel(const int* __restrict__ src,
                                                   const int* __restrict__ dst,
                                                   unsigned int* __restrict__ Hs,
                                                   unsigned int* __restrict__ Hd) {
    __shared__ unsigned hs[NBUCKP], hd[NBUCKP];
    int t = threadIdx.x;
    for (int i = t; i < NBUCKP; i += 512) { hs[i] = 0u; hd[i] = 0u; }
    __syncthreads();
    int base = blockIdx.x * CH4;
    for (int i = base + t; i < base + CH4; i += 512) {
        const int4 s4 = reinterpret_cast<const int4*>(src)[i];
        const int4 d4 = reinterpret_cast<const int4*>(dst)[i];
        atomicAdd(&hs[(unsigned)s4.x >> BSH], 1u);
        atomicAdd(&hs[(unsigned)s4.y >> BSH], 1u);
        atomicAdd(&hs[(unsigned)s4.z >> BSH], 1u);
        atomicAdd(&hs[(unsigned)s4.w >> BSH], 1u);
        atomicAdd(&hd[(unsigned)d4.x >> BSH], 1u);
        atomicAdd(&hd[(unsigned)d4.y >> BSH], 1u);
        atomicAdd(&hd[(unsigned)d4.z >> BSH], 1u);
        atomicAdd(&hd[(unsigned)d4.w >> BSH], 1u);
    }
    __syncthreads();
    unsigned int* rs = Hs + (size_t)blockIdx.x * NBUCKP;
    unsigned int* rd = Hd + (size_t)blockIdx.x * NBUCKP;
    for (int i = t; i < NBUCKP; i += 512) { rs[i] = hs[i]; rd[i] = hd[i]; }
}

// ---------------------------------------------------------------------------
// Phase 2a (fused s+d): per-bucket exclusive scan over the NB blocks (in
// place) + totals. Grid = 2*NBUCKP; block demux picks the array.
// ---------------------------------------------------------------------------
__global__ void __launch_bounds__(256) colscan2_kernel(unsigned int* __restrict__ Hs,
                                                       unsigned int* __restrict__ Hd,
                                                       unsigned int* __restrict__ total_s,
                                                       unsigned int* __restrict__ total_d) {
    __shared__ unsigned sh[256];
    int arr = (blockIdx.x >= NBUCKP) ? 1 : 0;
    int b = blockIdx.x - arr * NBUCKP;
    unsigned int* H     = arr ? Hd : Hs;
    unsigned int* total = arr ? total_d : total_s;
    int t = threadIdx.x;
    unsigned v = (t < NB) ? H[(size_t)t * NBUCKP + b] : 0u;
    sh[t] = v;
    __syncthreads();
    for (int off = 1; off < 256; off <<= 1) {
        unsigned x = (t >= off) ? sh[t - off] : 0u;
        __syncthreads();
        sh[t] += x;
        __syncthreads();
    }
    if (t < NB) H[(size_t)t * NBUCKP + b] = sh[t] - v;   // exclusive
    if (t == NB - 1) total[b] = sh[t];
}

// ---------------------------------------------------------------------------
// Phase 2b: exclusive scan of the two totals arrays -> ORDERED bucket bases.
// Ordered bases are required: R18 showed atomic (unordered) bases double
// gsum's FETCH (74 -> 142 MB) by destroying dbuck segment adjacency.
// ---------------------------------------------------------------------------
__global__ void __launch_bounds__(1024) totscan_kernel(const unsigned int* __restrict__ total_s,
                                                       unsigned int* __restrict__ cbase_s,
                                                       const unsigned int* __restrict__ total_d,
                                                       unsigned int* __restrict__ cbase_d) {
    __shared__ unsigned sh[1024];
    __shared__ unsigned carry;
    int t = threadIdx.x;
    for (int arr = 0; arr < 2; ++arr) {
        const unsigned int* tot = arr ? total_d : total_s;
        unsigned int* cb = arr ? cbase_d : cbase_s;
        if (t == 0) carry = 0u;
        __syncthreads();
        for (int chunk = 0; chunk < NBUCKP; chunk += 1024) {
            int i = chunk + t;
            unsigned v = (i < NBUCKP) ? tot[i] : 0u;
            sh[t] = v;
            __syncthreads();
            for (int off = 1; off < 1024; off <<= 1) {
                unsigned x = (t >= off) ? sh[t - off] : 0u;
                __syncthreads();
                sh[t] += x;
                __syncthreads();
            }
            unsigned c0 = carry;
            if (i < NBUCKP) cb[i] = c0 + sh[t] - v;
            __syncthreads();
            if (t == 1023) carry = c0 + sh[1023];
            __syncthreads();
        }
    }
}

// ---------------------------------------------------------------------------
// Phase 3: scatter edges into bucket-sorted arrays (int4 edge loads, LDS
// cursors, run-coalesced global writes, zero global atomics).
// sbuck (uint8): srcLocal; dbuck: dstLocal<<17|src
// ---------------------------------------------------------------------------
__global__ void __launch_bounds__(512) scatter_kernel(const int* __restrict__ src,
                                                      const int* __restrict__ dst,
                                                      const unsigned int* __restrict__ Hs,
                                                      const unsigned int* __restrict__ Hd,
                                                      const unsigned int* __restrict__ cbase_s,
                                                      const unsigned int* __restrict__ cbase_d,
                                                      unsigned char* __restrict__ sbuck,
                                                      unsigned int* __restrict__ dbuck) {
    __shared__ unsigned cs[NBUCKP], cd[NBUCKP];
    int t = threadIdx.x;
    int blk = blockIdx.x;
    const unsigned int* rs = Hs + (size_t)blk * NBUCKP;
    const unsigned int* rd = Hd + (size_t)blk * NBUCKP;
    for (int i = t; i < NBUCKP; i += 512) {
        cs[i] = cbase_s[i] + rs[i];
        cd[i] = cbase_d[i] + rd[i];
    }
    __syncthreads();
    int base = blk * CH4;
    for (int i = base + t; i < base + CH4; i += 512) {
        const int4 s4 = reinterpret_cast<const int4*>(src)[i];
        const int4 d4 = reinterpret_cast<const int4*>(dst)[i];
        #define SCAT1(S, Dd)                                              \
            {                                                             \
                unsigned ps = atomicAdd(&cs[(unsigned)(S) >> BSH], 1u);   \
                sbuck[ps] = (unsigned char)((unsigned)(S) & (BNODES - 1)); \
                unsigned pd = atomicAdd(&cd[(unsigned)(Dd) >> BSH], 1u);  \
                dbuck[pd] = (((unsigned)(Dd) & (BNODES - 1)) << 17) | (unsigned)(S); \
            }
        SCAT1(s4.x, d4.x)
        SCAT1(s4.y, d4.y)
        SCAT1(s4.z, d4.z)
        SCAT1(s4.w, d4.w)
        #undef SCAT1
    }
}

// ---------------------------------------------------------------------------
// Phase 4a (fused degcnt + g): per src-bucket, LDS-count out-degrees from
// sbuck, then g[r] = bf16( (feat[r]*rsqrt(max(deg,1))) @ W^T ) for the
// bucket's 64 nodes. W-row load hoisted before the sync to overlap.
// ---------------------------------------------------------------------------
__global__ void __launch_bounds__(256) gprep_kernel(const unsigned char* __restrict__ sbuck,
                                                    const unsigned int* __restrict__ cbase_s,
                                                    const unsigned int* __restrict__ total_s,
                                                    const float* __restrict__ feat,
                                                    const float* __restrict__ W,
                                                    unsigned short* __restrict__ g) {
    __shared__ unsigned cnt[BNODES];
    int bk = blockIdx.x;
    int t = threadIdx.x;
    int w = t >> 6;
    int lane = t & 63;
    if (t < BNODES) cnt[t] = 0u;
    __syncthreads();
    unsigned base = cbase_s[bk];
    unsigned n = total_s[bk];
    for (unsigned i = t; i < n; i += 256) {
        atomicAdd(&cnt[sbuck[base + i]], 1u);   // LDS atomic
    }

    float wreg[D];
    #pragma unroll
    for (int q = 0; q < 16; ++q) {
        const float4 t4 = *reinterpret_cast<const float4*>(&W[(size_t)lane * D + q * 4]);
        wreg[q * 4 + 0] = t4.x;
        wreg[q * 4 + 1] = t4.y;
        wreg[q * 4 + 2] = t4.z;
        wreg[q * 4 + 3] = t4.w;
    }
    __syncthreads();

    for (int nl = w; nl < BNODES; nl += 4) {
        int node = bk * BNODES + nl;
        if (node >= N_NODES) break;          // wave-uniform
        unsigned dg = cnt[nl];
        float sc = rsqrtf((float)(dg > 0u ? dg : 1u));
        float fv = feat[(size_t)node * D + lane] * sc;
        float o = 0.f;
        #pragma unroll
        for (int k = 0; k < D; ++k) {
            float fk = __int_as_float(
                __builtin_amdgcn_readlane(__float_as_int(fv), k));
            o += fk * wreg[k];
        }
        g[(size_t)node * D + lane] = f2bf_rne(o);
    }
}

// ---------------------------------------------------------------------------
// Phase 4b: per dst-bucket fused LDS-CSR + gather-sum + bias + rsqrt(deg_in).
// R13-proven: 256 threads, ONE block per bucket, dual-node interleave.
// ---------------------------------------------------------------------------
__global__ void __launch_bounds__(256) gsum_bucket(const unsigned short* __restrict__ g,
                                                   const unsigned int* __restrict__ dbuck,
                                                   const unsigned int* __restrict__ cbase_d,
                                                   const unsigned int* __restrict__ total_d,
                                                   const float* __restrict__ b,
                                                   float* __restrict__ out) {
    __shared__ int binned[BCAP];
    __shared__ unsigned cnt[BNODES], offs[BNODES], cur[BNODES];
    int bk = blockIdx.x;
    int t = threadIdx.x;
    int w = t >> 6;
    int lane = t & 63;
    int slot = lane >> 3;
    int sub  = lane & 7;

    if (t < BNODES) cnt[t] = 0u;
    __syncthreads();

    unsigned base = cbase_d[bk];
    unsigned n = total_d[bk];
    if (n > (unsigned)BCAP) n = BCAP;   // astronomically improbable clamp

    // count pass
    for (unsigned i = t; i < n; i += 256) {
        atomicAdd(&cnt[dbuck[base + i] >> 17], 1u);   // LDS atomic
    }
    __syncthreads();
    // inclusive scan of cnt[64] -> offs
    if (t < BNODES) offs[t] = cnt[t];
    __syncthreads();
    for (int off = 1; off < BNODES; off <<= 1) {
        unsigned x = (t < BNODES && t >= off) ? offs[t - off] : 0u;
        __syncthreads();
        if (t < BNODES) offs[t] += x;
        __syncthreads();
    }
    if (t < BNODES) cur[t] = offs[t] - cnt[t];        // exclusive base
    __syncthreads();
    // place pass
    for (unsigned i = t; i < n; i += 256) {
        unsigned p = dbuck[base + i];
        unsigned d = p >> 17;
        unsigned pos = atomicAdd(&cur[d], 1u);        // LDS atomic
        binned[pos] = (int)(p & 0x1FFFFu);
    }
    __syncthreads();

    float breg = b[sub * 8 + slot];
    // two nodes per wave-iteration: nlA in [0,32), nlB = nlA+32
    for (int j = 0; j < 8; ++j) {
        int nlA = w + 4 * j;
        int nlB = nlA + 32;
        int nodeA = bk * BNODES + nlA;
        int nodeB = bk * BNODES + nlB;
        bool okA = (nodeA < N_NODES);
        bool okB = (nodeB < N_NODES);
        unsigned degA = okA ? cnt[nlA] : 0u;
        unsigned degB = okB ? cnt[nlB] : 0u;
        unsigned eoffA = okA ? (offs[nlA] - degA) : 0u;
        unsigned eoffB = okB ? (offs[nlB] - degB) : 0u;
        unsigned dmax = degA > degB ? degA : degB;

        float accA[8], accB[8];
        #pragma unroll
        for (int q = 0; q < 8; ++q) { accA[q] = 0.f; accB[q] = 0.f; }

        for (unsigned e = 0; e < dmax; e += 8u) {
            unsigned es = e + (unsigned)slot;
            if (es < degA) {
                int s = binned[eoffA + es];            // 8-lane LDS broadcast
                const ushort8v v = *reinterpret_cast<const ushort8v*>(
                    &g[(size_t)s * D + sub * 8]);
                #pragma unroll
                for (int q = 0; q < 8; ++q)
                    accA[q] += __uint_as_float((unsigned)v[q] << 16);
            }
            if (es < degB) {
                int s = binned[eoffB + es];
                const ushort8v v = *reinterpret_cast<const ushort8v*>(
                    &g[(size_t)s * D + sub * 8]);
                #pragma unroll
                for (int q = 0; q < 8; ++q)
                    accB[q] += __uint_as_float((unsigned)v[q] << 16);
            }
        }

        #pragma unroll
        for (int q = 0; q < 8; ++q) {
            accA[q] += __shfl_xor(accA[q], 8);
            accA[q] += __shfl_xor(accA[q], 16);
            accA[q] += __shfl_xor(accA[q], 32);
            accB[q] += __shfl_xor(accB[q], 8);
            accB[q] += __shfl_xor(accB[q], 16);
            accB[q] += __shfl_xor(accB[q], 32);
        }
        float redA = (slot == 0) ? accA[0] : (slot == 1) ? accA[1] :
                     (slot == 2) ? accA[2] : (slot == 3) ? accA[3] :
                     (slot == 4) ? accA[4] : (slot == 5) ? accA[5] :
                     (slot == 6) ? accA[6] : accA[7];
        float redB = (slot == 0) ? accB[0] : (slot == 1) ? accB[1] :
                     (slot == 2) ? accB[2] : (slot == 3) ? accB[3] :
                     (slot == 4) ? accB[4] : (slot == 5) ? accB[5] :
                     (slot == 6) ? accB[6] : accB[7];
        int X = sub * 8 + slot;
        if (okA) {
            float rs = rsqrtf((float)(degA > 0u ? degA : 1u));
            __builtin_nontemporal_store((redA + breg) * rs,
                                        out + (size_t)nodeA * D + X);
        }
        if (okB) {
            float rs = rsqrtf((float)(degB > 0u ? degB : 1u));
            __builtin_nontemporal_store((redB + breg) * rs,
                                        out + (size_t)nodeB * D + X);
        }
    }
}

// ===========================================================================
// Tier B fallback (R7 path): partitioned atomics + CSR + h table + gather/GEMM
// ===========================================================================
__global__ void __launch_bounds__(256) deg2_part(const int* __restrict__ src,
                                                 const int* __restrict__ dst,
                                                 unsigned int* __restrict__ deg_out,
                                                 unsigned int* __restrict__ deg_in) {
    int part  = blockIdx.x & (NPART - 1);
    int chunk = blockIdx.x >> 3;
    unsigned lo = (unsigned)(part * PART_N);
    int base = chunk * (TOTAL_I4 / 250);
    for (int i = base + (int)threadIdx.x; i < base + (TOTAL_I4 / 250); i += 256) {
        const int4 s4 = reinterpret_cast<const int4*>(src)[i];
        const int4 d4 = reinterpret_cast<const int4*>(dst)[i];
        if ((unsigned)(s4.x - lo) < (unsigned)PART_N) atomicAdd(&deg_out[s4.x], 1u);
        if ((unsigned)(s4.y - lo) < (unsigned)PART_N) atomicAdd(&deg_out[s4.y], 1u);
        if ((unsigned)(s4.z - lo) < (unsigned)PART_N) atomicAdd(&deg_out[s4.z], 1u);
        if ((unsigned)(s4.w - lo) < (unsigned)PART_N) atomicAdd(&deg_out[s4.w], 1u);
        if ((unsigned)(d4.x - lo) < (unsigned)PART_N) atomicAdd(&deg_in[d4.x], 1u);
        if ((unsigned)(d4.y - lo) < (unsigned)PART_N) atomicAdd(&deg_in[d4.y], 1u);
        if ((unsigned)(d4.z - lo) < (unsigned)PART_N) atomicAdd(&deg_in[d4.z], 1u);
        if ((unsigned)(d4.w - lo) < (unsigned)PART_N) atomicAdd(&deg_in[d4.w], 1u);
    }
}

__global__ void __launch_bounds__(SCAN_BS) scan1_kernel(
        const unsigned int* __restrict__ in,
        unsigned int* __restrict__ out,
        unsigned int* __restrict__ partials, int n) {
    __shared__ unsigned int ssum[SCAN_BS];
    int t = threadIdx.x;
    int base = blockIdx.x * SCAN_TILE + t * SCAN_ITEMS;
    unsigned int v[SCAN_ITEMS];
    unsigned int s = 0;
    #pragma unroll
    for (int k = 0; k < SCAN_ITEMS; ++k) {
        v[k] = (base + k < n) ? in[base + k] : 0u;
        s += v[k];
    }
    ssum[t] = s;
    __syncthreads();
    for (int off = 1; off < SCAN_BS; off <<= 1) {
        unsigned int x = (t >= off) ? ssum[t - off] : 0u;
        __syncthreads();
        ssum[t] += x;
        __syncthreads();
    }
    unsigned int excl = (t == 0) ? 0u : ssum[t - 1];
    if (t == SCAN_BS - 1) partials[blockIdx.x] = ssum[t];
    unsigned int run = excl;
    #pragma unroll
    for (int k = 0; k < SCAN_ITEMS; ++k) {
        if (base + k < n) out[base + k] = run;
        run += v[k];
    }
}

__global__ void __launch_bounds__(128) scan2_kernel(
        unsigned int* __restrict__ partials, int nb) {
    __shared__ unsigned int sh[128];
    int t = threadIdx.x;
    unsigned int v = (t < nb) ? partials[t] : 0u;
    sh[t] = v;
    __syncthreads();
    for (int off = 1; off < 128; off <<= 1) {
        unsigned int x = (t >= off) ? sh[t - off] : 0u;
        __syncthreads();
        sh[t] += x;
        __syncthreads();
    }
    if (t < nb) partials[t] = (t == 0) ? 0u : sh[t - 1];
}

__global__ void scan3_kernel(unsigned int* __restrict__ offsets,
                             const unsigned int* __restrict__ partials,
                             unsigned int* __restrict__ cursor, int n) {
    int i = blockIdx.x * blockDim.x + threadIdx.x;
    if (i < n) {
        unsigned int v = offsets[i] + partials[i / SCAN_TILE];
        offsets[i] = v;
        cursor[i]  = v;
    }
    if (i == 0) offsets[n] = N_EDGES;
}

__global__ void __launch_bounds__(256) place_part(const int* __restrict__ src,
                                                  const int* __restrict__ dst,
                                                  unsigned int* __restrict__ cursor,
                                                  int* __restrict__ sorted_src) {
    int part  = blockIdx.x & (NPART - 1);
    int chunk = blockIdx.x >> 3;
    unsigned lo = (unsigned)(part * PART_N);
    int base = chunk * (TOTAL_I4 / 250);
    for (int i = base + (int)threadIdx.x; i < base + (TOTAL_I4 / 250); i += 256) {
        const int4 s4 = reinterpret_cast<const int4*>(src)[i];
        const int4 d4 = reinterpret_cast<const int4*>(dst)[i];
        #define PLACE1(S, Dd)                                             \
            if ((unsigned)((unsigned)(Dd) - lo) < (unsigned)PART_N) {     \
                unsigned p = atomicAdd(&cursor[(Dd)], 1u);                \
                sorted_src[p] = (S);                                      \
            }
        PLACE1(s4.x, d4.x)
        PLACE1(s4.y, d4.y)
        PLACE1(s4.z, d4.z)
        PLACE1(s4.w, d4.w)
        #undef PLACE1
    }
}

__global__ void h_kernel(const float* __restrict__ feat,
                         const unsigned int* __restrict__ deg_out,
                         unsigned short* __restrict__ h) {
    int tid = blockIdx.x * blockDim.x + threadIdx.x;
    if (tid >= N_NODES * 16) return;
    int node = tid >> 4;
    unsigned int dg = deg_out[node];
    float sc = rsqrtf((float)(dg > 0u ? dg : 1u));
    const float4 v = *reinterpret_cast<const float4*>(&feat[(size_t)tid * 4]);
    ushort4 o;
    o.x = f2bf_rne(v.x * sc);
    o.y = f2bf_rne(v.y * sc);
    o.z = f2bf_rne(v.z * sc);
    o.w = f2bf_rne(v.w * sc);
    *reinterpret_cast<ushort4*>(&h[(size_t)tid * 4]) = o;
}

__global__ void __launch_bounds__(256) gg2_kernel(
        const unsigned short* __restrict__ h,
        const int* __restrict__ sorted_src,
        const unsigned int* __restrict__ offsets,
        const float* __restrict__ W,
        const float* __restrict__ b,
        float* __restrict__ out) {
    int t = threadIdx.x;
    int w = t >> 6;
    int lane = t & 63;
    int slot = lane >> 3;
    int sub  = lane & 7;

    float wreg[D];
    #pragma unroll
    for (int q = 0; q < 16; ++q) {
        const float4 t4 = *reinterpret_cast<const float4*>(&W[(size_t)lane * D + q * 4]);
        wreg[q * 4 + 0] = t4.x;
        wreg[q * 4 + 1] = t4.y;
        wreg[q * 4 + 2] = t4.z;
        wreg[q * 4 + 3] = t4.w;
    }
    float breg = b[lane];

    for (int r = blockIdx.x * 4 + w; r < N_NODES; r += GK_BLOCKS * 4) {
        unsigned int beg = offsets[r];
        unsigned int end = offsets[r + 1];
        unsigned int deg = end - beg;

        float acc[8];
        #pragma unroll
        for (int j = 0; j < 8; ++j) acc[j] = 0.f;

        for (unsigned int base = beg; base < end; base += 64u) {
            int count = (int)(end - base);
            if (count > 64) count = 64;
            int myidx = (lane < count) ? sorted_src[base + lane] : 0;
            for (int e = 0; e < count; e += 8) {
                int es = e + slot;
                int s = __shfl(myidx, es);
                if (es < count) {
                    const ushort8v v = *reinterpret_cast<const ushort8v*>(
                        &h[(size_t)s * D + sub * 8]);
                    #pragma unroll
                    for (int j = 0; j < 8; ++j) {
                        acc[j] += __uint_as_float((unsigned)v[j] << 16);
                    }
                }
            }
        }

        #pragma unroll
        for (int j = 0; j < 8; ++j) {
            acc[j] += __shfl_xor(acc[j], 8);
            acc[j] += __shfl_xor(acc[j], 16);
            acc[j] += __shfl_xor(acc[j], 32);
        }

        float o = breg;
        #pragma unroll
        for (int k = 0; k < D; ++k) {
            float av = __int_as_float(
                __builtin_amdgcn_readlane(__float_as_int(acc[k & 7]), k >> 3));
            o += av * wreg[k];
        }

        out[(size_t)r * D + lane] = o * rsqrtf((float)(deg > 0u ? deg : 1u));
    }
}

// ---------------------------------------------------------------------------
extern "C" void kernel_launch(void* const* d_in, const int* in_sizes, int n_in,
                              void* d_out, int out_size, void* d_ws, size_t ws_size,
                              hipStream_t stream) {
    const float* feat = (const float*)d_in[0];
    const int*   src  = (const int*)d_in[1];
    const int*   dst  = (const int*)d_in[2];
    const float* W    = (const float*)d_in[3];
    const float* b    = (const float*)d_in[4];
    float* out = (float*)d_out;

    // --- Tier A layout (u32 units unless noted) ---
    {
        unsigned int* Hs      = (unsigned int*)d_ws;                    // NB*NBUCKP
        unsigned int* Hd      = Hs + (size_t)NB * NBUCKP;
        unsigned int* total_s = Hd + (size_t)NB * NBUCKP;               // NBUCKP
        unsigned int* cbase_s = total_s + NBUCKP;
        unsigned int* total_d = cbase_s + NBUCKP;
        unsigned int* cbase_d = total_d + NBUCKP;
        unsigned char* sbuck  = (unsigned char*)(cbase_d + NBUCKP);     // N_EDGES bytes
        unsigned int* dbuck   = (unsigned int*)(sbuck + N_EDGES);       // N_EDGES u32
        unsigned short* g     = (unsigned short*)(dbuck + N_EDGES);     // N*64 bf16
        size_t need_A = ((size_t)2 * NB * NBUCKP + 4 * NBUCKP) * 4
                        + (size_t)N_EDGES                                 // sbuck bytes
                        + (size_t)N_EDGES * 4                             // dbuck
                        + (size_t)N_NODES * D * 2;                        // g
        if (ws_size >= need_A) {
            hist_kernel<<<NB, 512, 0, stream>>>(src, dst, Hs, Hd);
            colscan2_kernel<<<2 * NBUCKP, 256, 0, stream>>>(Hs, Hd, total_s, total_d);
            totscan_kernel<<<1, 1024, 0, stream>>>(total_s, cbase_s, total_d, cbase_d);
            scatter_kernel<<<NB, 512, 0, stream>>>(src, dst, Hs, Hd,
                                                   cbase_s, cbase_d, sbuck, dbuck);
            gprep_kernel<<<NBUCK, 256, 0, stream>>>(sbuck, cbase_s, total_s, feat, W, g);
            gsum_bucket<<<NBUCK, 256, 0, stream>>>(g, dbuck, cbase_d, total_d, b, out);
            return;
        }
    }

    // --- Tier B layout (R7 fallback path), ~21 MB ---
    unsigned int* deg_out  = (unsigned int*)d_ws;
    unsigned int* deg_in   = deg_out + N_NODES;
    unsigned int* offsets  = deg_in + N_NODES;
    unsigned int* cursor   = offsets + N_NODES + 1;
    unsigned int* partials = cursor + N_NODES;
    size_t hdr = (size_t)(4 * N_NODES + 1 + 128);
    hdr = (hdr + 3u) & ~(size_t)3;
    int* sorted_src = (int*)d_ws + hdr;
    size_t hoff = hdr + N_EDGES;
    unsigned short* h = (unsigned short*)((unsigned int*)d_ws + hoff);

    hipMemsetAsync(d_ws, 0, (size_t)2 * N_NODES * sizeof(unsigned int), stream);
    deg2_part<<<2000, 256, 0, stream>>>(src, dst, deg_out, deg_in);
    scan1_kernel<<<SCAN_NBLK, SCAN_BS, 0, stream>>>(deg_in, offsets, partials, N_NODES);
    scan2_kernel<<<1, 128, 0, stream>>>(partials, SCAN_NBLK);
    scan3_kernel<<<(N_NODES + 255) / 256, 256, 0, stream>>>(offsets, partials, cursor, N_NODES);
    h_kernel<<<(N_NODES * 16 + 255) / 256, 256, 0, stream>>>(feat, deg_out, h);
    place_part<<<2000, 256, 0, stream>>>(src, dst, cursor, sorted_src);
    gg2_kernel<<<GK_BLOCKS, 256, 0, stream>>>(h, sorted_src, offsets, W, b, out);
}